// Round 1
// 3029.297 us; speedup vs baseline: 1.4688x; 1.4688x over previous
//
#include <hip/hip_runtime.h>
#include <cstddef>

namespace {

constexpr int B  = 4;
constexpr int L  = 2048;
constexpr int D  = 1024;
constexpr int H  = 16;
constexpr int DK = 64;              // == DV
constexpr int HD = H * DK;          // 1024
constexpr float INV_TEMP = 0.125f;  // 1/8
constexpr size_t NH = (size_t)B * H * L * DK;  // 8,388,608 floats per head-tensor
constexpr int NROWS = B * H * L;    // 131072 softmax rows
constexpr int NJT = L / 128;        // 16 j-tiles per row

// XOR swizzle for row-major [row][64] tiles read row-per-lane-group:
// spreads the 4/8 distinct row-addresses of one instruction across banks.
__device__ __forceinline__ int swzc(int r, int c) {
    return c ^ (((r >> 3) & 7) << 2);
}

// ---------------------------------------------------------------------------
// Projection GEMM: outh[b,h,l,d] = (X[m,:] @ W[:,n] + bias[n]) * scale
// BM=BN=128, BK=64, 256 threads, 8x8 micro-tile. A swizzled row-major in LDS.
// ---------------------------------------------------------------------------
__global__ __launch_bounds__(256, 2)
void gemm_proj(const float* __restrict__ X, const float* __restrict__ W,
               const float* __restrict__ bias, float* __restrict__ outh,
               float scale)
{
    __shared__ float As[128][64];   // [m][k], swizzled cols
    __shared__ float Bs[64][128];   // [k][n], linear
    const int tid = threadIdx.x;
    const int tx = tid & 15, ty = tid >> 4;
    const int m0 = blockIdx.x << 7;
    const int n0 = blockIdx.y << 7;
    float c[8][8] = {};

    for (int k0 = 0; k0 < D; k0 += 64) {
#pragma unroll
        for (int it = 0; it < 8; ++it) {
            const int idx = (it << 10) + (tid << 2);
            {   // A tile: 128 x 64
                const int r = idx >> 6, cb = idx & 63;
                *(float4*)&As[r][swzc(r, cb)] =
                    *(const float4*)(X + (size_t)(m0 + r) * D + k0 + cb);
            }
            {   // B tile: 64 x 128
                const int r = idx >> 7, cb = idx & 127;
                *(float4*)&Bs[r][cb] =
                    *(const float4*)(W + (size_t)(k0 + r) * HD + n0 + cb);
            }
        }
        __syncthreads();
        const int swA = (ty & 7) << 2;
#pragma unroll 2
        for (int kk = 0; kk < 64; kk += 4) {
            float4 a[8];
#pragma unroll
            for (int i = 0; i < 8; ++i)
                a[i] = *(const float4*)&As[(ty << 3) + i][kk ^ swA];
            float bl[4][4], bh_[4][4];
#pragma unroll
            for (int t = 0; t < 4; ++t) {
                const float4 b0 = *(const float4*)&Bs[kk + t][tx << 2];
                const float4 b1 = *(const float4*)&Bs[kk + t][(tx << 2) + 64];
                bl[t][0] = b0.x; bl[t][1] = b0.y; bl[t][2] = b0.z; bl[t][3] = b0.w;
                bh_[t][0] = b1.x; bh_[t][1] = b1.y; bh_[t][2] = b1.z; bh_[t][3] = b1.w;
            }
#pragma unroll
            for (int i = 0; i < 8; ++i) {
                const float af[4] = {a[i].x, a[i].y, a[i].z, a[i].w};
#pragma unroll
                for (int j = 0; j < 4; ++j) {
#pragma unroll
                    for (int t = 0; t < 4; ++t) {
                        c[i][j]     = fmaf(af[t], bl[t][j], c[i][j]);
                        c[i][j + 4] = fmaf(af[t], bh_[t][j], c[i][j + 4]);
                    }
                }
            }
        }
        __syncthreads();
    }

    // epilogue: col groups [n0+tx*4 .. +3] and [n0+64+tx*4 .. +3]; each inside one head
    const int nlo = n0 + (tx << 2);
    const int nhi = nlo + 64;
    const float4 blo = *(const float4*)(bias + nlo);
    const float4 bhi = *(const float4*)(bias + nhi);
    const int hlo = nlo >> 6, hhi = nhi >> 6;
    const int dd  = tx << 2;
#pragma unroll
    for (int i = 0; i < 8; ++i) {
        const int m = m0 + (ty << 3) + i;
        const int b = m >> 11;           // / 2048
        const int l = m & (L - 1);
        float4 r0, r1;
        r0.x = (c[i][0] + blo.x) * scale; r0.y = (c[i][1] + blo.y) * scale;
        r0.z = (c[i][2] + blo.z) * scale; r0.w = (c[i][3] + blo.w) * scale;
        r1.x = (c[i][4] + bhi.x) * scale; r1.y = (c[i][5] + bhi.y) * scale;
        r1.z = (c[i][6] + bhi.z) * scale; r1.w = (c[i][7] + bhi.w) * scale;
        *(float4*)(outh + ((((size_t)b * H + hlo) * L + l) << 6) + dd) = r0;
        *(float4*)(outh + ((((size_t)b * H + hhi) * L + l) << 6) + dd) = r1;
    }
}

// ---------------------------------------------------------------------------
// Scores: att[bh,q,j] = sum_d Qh[bh,q,d]*Kh[bh,j,d] (Q pre-scaled), masked -1e9.
// 128x128 tile, K=64 one-shot, 8x8 micro-tile. Both tiles staged row-major
// (K read row-per-j, no transpose). Also emits per-tile softmax partials
// (rowmax, sum exp) into part[row][jt].
// ---------------------------------------------------------------------------
__global__ __launch_bounds__(256, 2)
void scores_kernel(const float* __restrict__ Qh, const float* __restrict__ Kh,
                   const int* __restrict__ mask, float* __restrict__ att,
                   float* __restrict__ part)
{
    __shared__ float As[128][64];   // [q][d], swizzled
    __shared__ float Bs[128][64];   // [j][d], swizzled
    const int tid = threadIdx.x;
    const int tx = tid & 15, ty = tid >> 4;
    const int j0 = blockIdx.x << 7;
    const int q0 = blockIdx.y << 7;
    const int bh = blockIdx.z;
    const int b  = bh >> 4;
    const float* Qb = Qh + (size_t)bh * L * DK;
    const float* Kb = Kh + (size_t)bh * L * DK;

#pragma unroll
    for (int it = 0; it < 8; ++it) {
        const int idx = (it << 10) + (tid << 2);
        const int r = idx >> 6, cb = idx & 63;
        const int cw = swzc(r, cb);
        *(float4*)&As[r][cw] = *(const float4*)(Qb + (size_t)(q0 + r) * DK + cb);
        *(float4*)&Bs[r][cw] = *(const float4*)(Kb + (size_t)(j0 + r) * DK + cb);
    }
    __syncthreads();

    float c[8][8] = {};
    const int swA = (ty & 7) << 2;
    const int swB = (tx & 7) << 2;
#pragma unroll 2
    for (int kk = 0; kk < 64; kk += 4) {
        float4 a[8], bb[8];
#pragma unroll
        for (int i = 0; i < 8; ++i)
            a[i] = *(const float4*)&As[(ty << 3) + i][kk ^ swA];
#pragma unroll
        for (int j = 0; j < 8; ++j)
            bb[j] = *(const float4*)&Bs[(tx << 3) + j][kk ^ swB];
#pragma unroll
        for (int i = 0; i < 8; ++i)
#pragma unroll
            for (int j = 0; j < 8; ++j) {
                c[i][j] = fmaf(a[i].x, bb[j].x, c[i][j]);
                c[i][j] = fmaf(a[i].y, bb[j].y, c[i][j]);
                c[i][j] = fmaf(a[i].z, bb[j].z, c[i][j]);
                c[i][j] = fmaf(a[i].w, bb[j].w, c[i][j]);
            }
    }

    const int jc = j0 + (tx << 3);
#pragma unroll
    for (int i = 0; i < 8; ++i) {
        const int q = q0 + (ty << 3) + i;
        const int* mp = mask + ((size_t)b * L + q) * L + jc;
        const int4 mA = *(const int4*)mp;
        const int4 mB = *(const int4*)(mp + 4);
        const float v0 = mA.x ? c[i][0] : -1e9f;
        const float v1 = mA.y ? c[i][1] : -1e9f;
        const float v2 = mA.z ? c[i][2] : -1e9f;
        const float v3 = mA.w ? c[i][3] : -1e9f;
        const float v4 = mB.x ? c[i][4] : -1e9f;
        const float v5 = mB.y ? c[i][5] : -1e9f;
        const float v6 = mB.z ? c[i][6] : -1e9f;
        const float v7 = mB.w ? c[i][7] : -1e9f;
        float* ap = att + ((size_t)bh * L + q) * L + jc;
        *(float4*)ap       = make_float4(v0, v1, v2, v3);
        *(float4*)(ap + 4) = make_float4(v4, v5, v6, v7);

        // per-row partial softmax stats across the 16 tx lanes (same ty group)
        float mx = fmaxf(fmaxf(fmaxf(v0, v1), fmaxf(v2, v3)),
                         fmaxf(fmaxf(v4, v5), fmaxf(v6, v7)));
        mx = fmaxf(mx, __shfl_xor(mx, 1, 16));
        mx = fmaxf(mx, __shfl_xor(mx, 2, 16));
        mx = fmaxf(mx, __shfl_xor(mx, 4, 16));
        mx = fmaxf(mx, __shfl_xor(mx, 8, 16));
        float sm = __expf(v0 - mx) + __expf(v1 - mx) + __expf(v2 - mx) +
                   __expf(v3 - mx) + __expf(v4 - mx) + __expf(v5 - mx) +
                   __expf(v6 - mx) + __expf(v7 - mx);
        sm += __shfl_xor(sm, 1, 16);
        sm += __shfl_xor(sm, 2, 16);
        sm += __shfl_xor(sm, 4, 16);
        sm += __shfl_xor(sm, 8, 16);
        if (tx == 0)
            *(float2*)(part + (((size_t)bh * L + q) * NJT + blockIdx.x) * 2) =
                make_float2(mx, sm);
    }
}

// ---------------------------------------------------------------------------
// Fold 16 per-tile partials into per-row (max, 1/sum). 16 lanes per row.
// ---------------------------------------------------------------------------
__global__ __launch_bounds__(256)
void rowstats_kernel(const float* __restrict__ part, float* __restrict__ stats)
{
    const int gid = blockIdx.x * 256 + threadIdx.x;
    const int row = gid >> 4;
    const int t   = gid & 15;
    const float2 p = *(const float2*)(part + ((size_t)row * NJT + t) * 2);
    float M = p.x;
    M = fmaxf(M, __shfl_xor(M, 1, 16));
    M = fmaxf(M, __shfl_xor(M, 2, 16));
    M = fmaxf(M, __shfl_xor(M, 4, 16));
    M = fmaxf(M, __shfl_xor(M, 8, 16));
    float s = p.y * __expf(p.x - M);
    s += __shfl_xor(s, 1, 16);
    s += __shfl_xor(s, 2, 16);
    s += __shfl_xor(s, 4, 16);
    s += __shfl_xor(s, 8, 16);
    if (t == 0)
        *(float2*)(stats + (size_t)row * 2) = make_float2(M, 1.0f / s);
}

// ---------------------------------------------------------------------------
// attv: normalize raw scores in place (exp(s-M)*invSum -> final att output)
// while staging, then O = P @ V. BM=128, BN=64, BK=64, 8x4 micro-tile.
// ---------------------------------------------------------------------------
__global__ __launch_bounds__(256, 3)
void attv_kernel(float* __restrict__ att, const float* __restrict__ Vh,
                 const float* __restrict__ stats, float* __restrict__ O)
{
    __shared__ float As[128][64];   // [q][k-sub], swizzled
    __shared__ float Bs[64][64];    // [k-sub][d]
    __shared__ float2 ss[128];
    const int tid = threadIdx.x;
    const int tx = tid & 15, ty = tid >> 4;
    const int m0 = blockIdx.x << 7;
    const int bh = blockIdx.y;
    float* Ab = att + (size_t)bh * L * L;
    const float* Vb = Vh + (size_t)bh * L * DK;

    if (tid < 128)
        ss[tid] = *(const float2*)(stats + ((size_t)bh * L + m0 + tid) * 2);
    __syncthreads();

    float c[8][4] = {};
    const int swA = (ty & 7) << 2;
    for (int k0 = 0; k0 < L; k0 += 64) {
#pragma unroll
        for (int it = 0; it < 8; ++it) {
            const int idx = (it << 10) + (tid << 2);
            const int r = idx >> 6, cb = idx & 63;
            float* gp = Ab + (size_t)(m0 + r) * L + k0 + cb;
            const float4 vv = *(const float4*)gp;
            const float2 s2 = ss[r];
            float4 p;
            p.x = __expf(vv.x - s2.x) * s2.y;
            p.y = __expf(vv.y - s2.x) * s2.y;
            p.z = __expf(vv.z - s2.x) * s2.y;
            p.w = __expf(vv.w - s2.x) * s2.y;
            *(float4*)gp = p;                       // final normalized att
            *(float4*)&As[r][swzc(r, cb)] = p;
        }
#pragma unroll
        for (int it = 0; it < 4; ++it) {
            const int idx = (it << 10) + (tid << 2);
            const int r = idx >> 6, cb = idx & 63;
            *(float4*)&Bs[r][cb] =
                *(const float4*)(Vb + (size_t)(k0 + r) * DK + cb);
        }
        __syncthreads();
#pragma unroll 2
        for (int kk = 0; kk < 64; kk += 4) {
            float4 a[8];
#pragma unroll
            for (int i = 0; i < 8; ++i)
                a[i] = *(const float4*)&As[(ty << 3) + i][kk ^ swA];
            float bf[4][4];
#pragma unroll
            for (int t = 0; t < 4; ++t) {
                const float4 b4 = *(const float4*)&Bs[kk + t][tx << 2];
                bf[t][0] = b4.x; bf[t][1] = b4.y; bf[t][2] = b4.z; bf[t][3] = b4.w;
            }
#pragma unroll
            for (int i = 0; i < 8; ++i) {
                const float af[4] = {a[i].x, a[i].y, a[i].z, a[i].w};
#pragma unroll
                for (int j = 0; j < 4; ++j)
#pragma unroll
                    for (int t = 0; t < 4; ++t)
                        c[i][j] = fmaf(af[t], bf[t][j], c[i][j]);
            }
        }
        __syncthreads();
    }
#pragma unroll
    for (int i = 0; i < 8; ++i) {
        const int m = m0 + (ty << 3) + i;
        *(float4*)(O + (((size_t)bh * L + m) << 6) + (tx << 2)) =
            make_float4(c[i][0], c[i][1], c[i][2], c[i][3]);
    }
}

// ---------------------------------------------------------------------------
// FC: out[m,n] = sum_k Oflat[m,k]*Wfc[k,n] + bfc[n] + resid[m,n]
// Same 128x128 / 8x8 structure as gemm_proj; A from head-major O.
// ---------------------------------------------------------------------------
__global__ __launch_bounds__(256, 2)
void fc_kernel(const float* __restrict__ O, const float* __restrict__ Wfc,
               const float* __restrict__ bfc, const float* __restrict__ resid,
               float* __restrict__ out)
{
    __shared__ float As[128][64];
    __shared__ float Bs[64][128];
    const int tid = threadIdx.x;
    const int tx = tid & 15, ty = tid >> 4;
    const int m0 = blockIdx.x << 7;
    const int n0 = blockIdx.y << 7;
    float c[8][8] = {};

    for (int k0 = 0; k0 < HD; k0 += 64) {
        const int h = k0 >> 6;   // one head per k-tile
#pragma unroll
        for (int it = 0; it < 8; ++it) {
            const int idx = (it << 10) + (tid << 2);
            {
                const int r = idx >> 6, cb = idx & 63;
                const int m = m0 + r;
                const int b = m >> 11, l = m & (L - 1);
                *(float4*)&As[r][swzc(r, cb)] =
                    *(const float4*)(O + ((((size_t)b * H + h) * L + l) << 6) + cb);
            }
            {
                const int r = idx >> 7, cb = idx & 127;
                *(float4*)&Bs[r][cb] =
                    *(const float4*)(Wfc + (size_t)(k0 + r) * D + n0 + cb);
            }
        }
        __syncthreads();
        const int swA = (ty & 7) << 2;
#pragma unroll 2
        for (int kk = 0; kk < 64; kk += 4) {
            float4 a[8];
#pragma unroll
            for (int i = 0; i < 8; ++i)
                a[i] = *(const float4*)&As[(ty << 3) + i][kk ^ swA];
            float bl[4][4], bh_[4][4];
#pragma unroll
            for (int t = 0; t < 4; ++t) {
                const float4 b0 = *(const float4*)&Bs[kk + t][tx << 2];
                const float4 b1 = *(const float4*)&Bs[kk + t][(tx << 2) + 64];
                bl[t][0] = b0.x; bl[t][1] = b0.y; bl[t][2] = b0.z; bl[t][3] = b0.w;
                bh_[t][0] = b1.x; bh_[t][1] = b1.y; bh_[t][2] = b1.z; bh_[t][3] = b1.w;
            }
#pragma unroll
            for (int i = 0; i < 8; ++i) {
                const float af[4] = {a[i].x, a[i].y, a[i].z, a[i].w};
#pragma unroll
                for (int j = 0; j < 4; ++j)
#pragma unroll
                    for (int t = 0; t < 4; ++t) {
                        c[i][j]     = fmaf(af[t], bl[t][j], c[i][j]);
                        c[i][j + 4] = fmaf(af[t], bh_[t][j], c[i][j + 4]);
                    }
            }
        }
        __syncthreads();
    }

    const int nlo = n0 + (tx << 2);
    const int nhi = nlo + 64;
    const float4 blo = *(const float4*)(bfc + nlo);
    const float4 bhi = *(const float4*)(bfc + nhi);
#pragma unroll
    for (int i = 0; i < 8; ++i) {
        const int m = m0 + (ty << 3) + i;
        const float4 q0v = *(const float4*)(resid + (size_t)m * D + nlo);
        const float4 q1v = *(const float4*)(resid + (size_t)m * D + nhi);
        float4 r0, r1;
        r0.x = c[i][0] + blo.x + q0v.x; r0.y = c[i][1] + blo.y + q0v.y;
        r0.z = c[i][2] + blo.z + q0v.z; r0.w = c[i][3] + blo.w + q0v.w;
        r1.x = c[i][4] + bhi.x + q1v.x; r1.y = c[i][5] + bhi.y + q1v.y;
        r1.z = c[i][6] + bhi.z + q1v.z; r1.w = c[i][7] + bhi.w + q1v.w;
        *(float4*)(out + (size_t)m * D + nlo) = r0;
        *(float4*)(out + (size_t)m * D + nhi) = r1;
    }
}

}  // namespace

extern "C" void kernel_launch(void* const* d_in, const int* in_sizes, int n_in,
                              void* d_out, int out_size, void* d_ws, size_t ws_size,
                              hipStream_t stream)
{
    const float* q    = (const float*)d_in[0];
    const float* k    = (const float*)d_in[1];
    const float* v    = (const float*)d_in[2];
    const int*   mask = (const int*)d_in[3];
    const float* Wq   = (const float*)d_in[4];
    const float* bq   = (const float*)d_in[5];
    const float* Wk   = (const float*)d_in[6];
    const float* bk   = (const float*)d_in[7];
    const float* Wv   = (const float*)d_in[8];
    const float* bv   = (const float*)d_in[9];
    const float* Wfc  = (const float*)d_in[10];
    const float* bfc  = (const float*)d_in[11];

    float* out = (float*)d_out;                   // [B,L,D]
    float* att = out + (size_t)B * L * D;         // [B,H,L,L]

    float* Qh = (float*)d_ws;       // [B,H,L,64]
    float* Kh = Qh + NH;
    float* Vh = Kh + NH;
    float* O  = Qh;                 // alias: Qh dead after scores_kernel
    float* stats = Kh;              // alias: Kh dead after scores_kernel (1 MB)
    float* part  = out;             // alias: out written only by fc at the end
                                    // (NROWS*NJT float2 = 16.8 MB < 33.5 MB)

    const dim3 blk(256);

    gemm_proj<<<dim3(64, 8), blk, 0, stream>>>(q, Wq, bq, Qh, INV_TEMP);
    gemm_proj<<<dim3(64, 8), blk, 0, stream>>>(k, Wk, bk, Kh, 1.0f);
    gemm_proj<<<dim3(64, 8), blk, 0, stream>>>(v, Wv, bv, Vh, 1.0f);

    scores_kernel<<<dim3(L / 128, L / 128, B * H), blk, 0, stream>>>(Qh, Kh, mask, att, part);
    rowstats_kernel<<<dim3(NROWS * 16 / 256), blk, 0, stream>>>(part, stats);
    attv_kernel<<<dim3(L / 128, B * H), blk, 0, stream>>>(att, Vh, stats, O);
    fc_kernel<<<dim3(64, 8), blk, 0, stream>>>(O, Wfc, bfc, q, out);
}

// Round 2
// 2804.594 us; speedup vs baseline: 1.5865x; 1.0801x over previous
//
#include <hip/hip_runtime.h>
#include <cstddef>

namespace {

constexpr int B  = 4;
constexpr int L  = 2048;
constexpr int D  = 1024;
constexpr int H  = 16;
constexpr int DK = 64;              // == DV
constexpr int HD = H * DK;          // 1024
constexpr float INV_TEMP = 0.125f;  // 1/8
constexpr size_t NH = (size_t)B * H * L * DK;  // 8,388,608 elements per head-tensor
constexpr int NROWS = B * H * L;    // 131072 softmax rows
constexpr int NJT = L / 128;        // 16 j-tiles per row

typedef __bf16 bf16;
typedef bf16 bf16x4 __attribute__((ext_vector_type(4)));
typedef bf16 bf16x8 __attribute__((ext_vector_type(8)));
typedef float f32x4 __attribute__((ext_vector_type(4)));

// XOR swizzle for row-major [row][64] fp32 tiles read row-per-lane-group.
__device__ __forceinline__ int swzc(int r, int c) {
    return c ^ (((r >> 3) & 7) << 2);
}

// ---------------------------------------------------------------------------
// Projection GEMM (fp32 core, bf16 output):
//   vmode==0: outh[b,h,l,d] = bf16((X@W + bias)[m,n] * scale), layout [bh][l][64]
//   vmode==1: transposed V:  outh[bh][d][l]  (B-operand layout for PV MFMA)
// BM=BN=128, BK=64, 256 threads, 8x8 micro-tile.
// ---------------------------------------------------------------------------
__global__ __launch_bounds__(256, 2)
void gemm_proj(const float* __restrict__ X, const float* __restrict__ W,
               const float* __restrict__ bias, bf16* __restrict__ outh,
               float scale, int vmode)
{
    __shared__ float As[128][64];   // [m][k], swizzled cols
    __shared__ float Bs[64][128];   // [k][n], linear
    const int tid = threadIdx.x;
    const int tx = tid & 15, ty = tid >> 4;
    const int m0 = blockIdx.x << 7;
    const int n0 = blockIdx.y << 7;
    float c[8][8] = {};

    for (int k0 = 0; k0 < D; k0 += 64) {
#pragma unroll
        for (int it = 0; it < 8; ++it) {
            const int idx = (it << 10) + (tid << 2);
            {   // A tile: 128 x 64
                const int r = idx >> 6, cb = idx & 63;
                *(float4*)&As[r][swzc(r, cb)] =
                    *(const float4*)(X + (size_t)(m0 + r) * D + k0 + cb);
            }
            {   // B tile: 64 x 128
                const int r = idx >> 7, cb = idx & 127;
                *(float4*)&Bs[r][cb] =
                    *(const float4*)(W + (size_t)(k0 + r) * HD + n0 + cb);
            }
        }
        __syncthreads();
        const int swA = (ty & 7) << 2;
#pragma unroll 2
        for (int kk = 0; kk < 64; kk += 4) {
            float4 a[8];
#pragma unroll
            for (int i = 0; i < 8; ++i)
                a[i] = *(const float4*)&As[(ty << 3) + i][kk ^ swA];
            float bl[4][4], bh_[4][4];
#pragma unroll
            for (int t = 0; t < 4; ++t) {
                const float4 b0 = *(const float4*)&Bs[kk + t][tx << 2];
                const float4 b1 = *(const float4*)&Bs[kk + t][(tx << 2) + 64];
                bl[t][0] = b0.x; bl[t][1] = b0.y; bl[t][2] = b0.z; bl[t][3] = b0.w;
                bh_[t][0] = b1.x; bh_[t][1] = b1.y; bh_[t][2] = b1.z; bh_[t][3] = b1.w;
            }
#pragma unroll
            for (int i = 0; i < 8; ++i) {
                const float af[4] = {a[i].x, a[i].y, a[i].z, a[i].w};
#pragma unroll
                for (int j = 0; j < 4; ++j) {
#pragma unroll
                    for (int t = 0; t < 4; ++t) {
                        c[i][j]     = fmaf(af[t], bl[t][j], c[i][j]);
                        c[i][j + 4] = fmaf(af[t], bh_[t][j], c[i][j + 4]);
                    }
                }
            }
        }
        __syncthreads();
    }

    if (vmode) {
        // transposed bf16 store: outh[bh][d][l]; block never straddles a batch
        const int b  = m0 >> 11;
        const int l0 = (m0 & (L - 1)) + (ty << 3);
#pragma unroll
        for (int j = 0; j < 8; ++j) {
            const int col = n0 + (tx << 2) + ((j < 4) ? j : 60 + j);
            const float bj = bias[col];
            bf16x8 rv;
#pragma unroll
            for (int i = 0; i < 8; ++i)
                rv[i] = (bf16)((c[i][j] + bj) * scale);
            *(bf16x8*)(outh + ((size_t)(b * H + (col >> 6)) * 64 + (col & 63)) * L + l0) = rv;
        }
    } else {
        const int nlo = n0 + (tx << 2);
        const int nhi = nlo + 64;
        const float4 blo = *(const float4*)(bias + nlo);
        const float4 bhi = *(const float4*)(bias + nhi);
        const int hlo = nlo >> 6, hhi = nhi >> 6;
        const int dlo = nlo & 63, dhi = nhi & 63;
#pragma unroll
        for (int i = 0; i < 8; ++i) {
            const int m = m0 + (ty << 3) + i;
            const int b = m >> 11;
            const int l = m & (L - 1);
            bf16x4 r0, r1;
            r0[0] = (bf16)((c[i][0] + blo.x) * scale);
            r0[1] = (bf16)((c[i][1] + blo.y) * scale);
            r0[2] = (bf16)((c[i][2] + blo.z) * scale);
            r0[3] = (bf16)((c[i][3] + blo.w) * scale);
            r1[0] = (bf16)((c[i][4] + bhi.x) * scale);
            r1[1] = (bf16)((c[i][5] + bhi.y) * scale);
            r1[2] = (bf16)((c[i][6] + bhi.z) * scale);
            r1[3] = (bf16)((c[i][7] + bhi.w) * scale);
            *(bf16x4*)(outh + ((((size_t)b * H + hlo) * L + l) << 6) + dlo) = r0;
            *(bf16x4*)(outh + ((((size_t)b * H + hhi) * L + l) << 6) + dhi) = r1;
        }
    }
}

// ---------------------------------------------------------------------------
// Scores via bf16 MFMA, no LDS, no barriers. 128x128 tile per block, 4 waves,
// each wave: 32 q-rows x 128 j (2x8 16x16 tiles, K=64 in two x32 chunks).
// Writes raw masked S + per-128-tile softmax partials.
// ---------------------------------------------------------------------------
__global__ __launch_bounds__(256)
void scores_kernel(const bf16* __restrict__ Qh, const bf16* __restrict__ Kh,
                   const int* __restrict__ mask, float* __restrict__ att,
                   float* __restrict__ part)
{
    const int tid  = threadIdx.x;
    const int lane = tid & 63;
    const int w    = tid >> 6;
    const int lr   = lane & 15;   // A-row / B-col within fragment
    const int lg   = lane >> 4;   // k-group (inputs) / row-group (C)
    const int j0 = blockIdx.x << 7;
    const int q0 = blockIdx.y << 7;
    const int bh = blockIdx.z;
    const int b  = bh >> 4;
    const bf16* Qb = Qh + (size_t)bh * L * DK;
    const bf16* Kb = Kh + (size_t)bh * L * DK;
    const int qw = q0 + (w << 5);

    f32x4 acc[2][8];
#pragma unroll
    for (int qt = 0; qt < 2; ++qt)
#pragma unroll
        for (int jt = 0; jt < 8; ++jt)
            acc[qt][jt] = (f32x4){0.f, 0.f, 0.f, 0.f};

#pragma unroll
    for (int kc = 0; kc < 2; ++kc) {
        bf16x8 a[2], kb[8];
#pragma unroll
        for (int qt = 0; qt < 2; ++qt)
            a[qt] = *(const bf16x8*)(Qb + (size_t)(qw + (qt << 4) + lr) * DK + (kc << 5) + (lg << 3));
#pragma unroll
        for (int jt = 0; jt < 8; ++jt)
            kb[jt] = *(const bf16x8*)(Kb + (size_t)(j0 + (jt << 4) + lr) * DK + (kc << 5) + (lg << 3));
#pragma unroll
        for (int qt = 0; qt < 2; ++qt)
#pragma unroll
            for (int jt = 0; jt < 8; ++jt)
                acc[qt][jt] = __builtin_amdgcn_mfma_f32_16x16x32_bf16(
                    a[qt], kb[jt], acc[qt][jt], 0, 0, 0);
    }

    // mask + write raw S + per-row partial (max, sum-exp) over this 128-j block
#pragma unroll
    for (int qt = 0; qt < 2; ++qt)
#pragma unroll
        for (int r = 0; r < 4; ++r) {
            const int q = qw + (qt << 4) + (lg << 2) + r;
            const int* mrow = mask + ((size_t)b * L + q) * L + j0 + lr;
            float* arow = att + ((size_t)bh * L + q) * L + j0 + lr;
            float vals[8];
#pragma unroll
            for (int jt = 0; jt < 8; ++jt) {
                const float vv = mrow[jt << 4] ? acc[qt][jt][r] : -1e9f;
                vals[jt] = vv;
                arow[jt << 4] = vv;
            }
            float mx = vals[0];
#pragma unroll
            for (int jt = 1; jt < 8; ++jt) mx = fmaxf(mx, vals[jt]);
            mx = fmaxf(mx, __shfl_xor(mx, 1, 16));
            mx = fmaxf(mx, __shfl_xor(mx, 2, 16));
            mx = fmaxf(mx, __shfl_xor(mx, 4, 16));
            mx = fmaxf(mx, __shfl_xor(mx, 8, 16));
            float sm = 0.f;
#pragma unroll
            for (int jt = 0; jt < 8; ++jt) sm += __expf(vals[jt] - mx);
            sm += __shfl_xor(sm, 1, 16);
            sm += __shfl_xor(sm, 2, 16);
            sm += __shfl_xor(sm, 4, 16);
            sm += __shfl_xor(sm, 8, 16);
            if (lr == 0)
                *(float2*)(part + (((size_t)bh * L + q) * NJT + blockIdx.x) * 2) =
                    make_float2(mx, sm);
        }
}

// ---------------------------------------------------------------------------
// Fold 16 per-tile partials into per-row (max, 1/sum). 16 lanes per row.
// ---------------------------------------------------------------------------
__global__ __launch_bounds__(256)
void rowstats_kernel(const float* __restrict__ part, float* __restrict__ stats)
{
    const int gid = blockIdx.x * 256 + threadIdx.x;
    const int row = gid >> 4;
    const int t   = gid & 15;
    const float2 p = *(const float2*)(part + ((size_t)row * NJT + t) * 2);
    float M = p.x;
    M = fmaxf(M, __shfl_xor(M, 1, 16));
    M = fmaxf(M, __shfl_xor(M, 2, 16));
    M = fmaxf(M, __shfl_xor(M, 4, 16));
    M = fmaxf(M, __shfl_xor(M, 8, 16));
    float s = p.y * __expf(p.x - M);
    s += __shfl_xor(s, 1, 16);
    s += __shfl_xor(s, 2, 16);
    s += __shfl_xor(s, 4, 16);
    s += __shfl_xor(s, 8, 16);
    if (t == 0)
        *(float2*)(stats + (size_t)row * 2) = make_float2(M, 1.0f / s);
}

// ---------------------------------------------------------------------------
// attv via bf16 MFMA, no LDS, no barriers. Per block: 128 q x 64 d, K=2048.
// Each lane loads its own raw-S A-fragment (32B contiguous), normalizes
// (exp(s-M)*invSum), writes final att back, feeds MFMA directly.
// V is pre-transposed [bh][d][L] bf16 -> contiguous B-fragments.
// ---------------------------------------------------------------------------
__global__ __launch_bounds__(256)
void attv_kernel(float* __restrict__ att, const bf16* __restrict__ Vt,
                 const float* __restrict__ stats, float* __restrict__ O)
{
    const int tid  = threadIdx.x;
    const int lane = tid & 63;
    const int w    = tid >> 6;
    const int lr   = lane & 15;
    const int lg   = lane >> 4;
    const int m0 = blockIdx.x << 7;
    const int bh = blockIdx.y;
    const int qw = m0 + (w << 5);
    float* Ab = att + (size_t)bh * L * L;
    const bf16* Vb = Vt + (size_t)bh * 64 * L;

    f32x4 acc[2][4];
#pragma unroll
    for (int qt = 0; qt < 2; ++qt)
#pragma unroll
        for (int dt = 0; dt < 4; ++dt)
            acc[qt][dt] = (f32x4){0.f, 0.f, 0.f, 0.f};

    float Mq[2], Iq[2];
#pragma unroll
    for (int qt = 0; qt < 2; ++qt) {
        const float2 s2 = *(const float2*)(stats + ((size_t)bh * L + qw + (qt << 4) + lr) * 2);
        Mq[qt] = s2.x; Iq[qt] = s2.y;
    }

    for (int k0 = 0; k0 < L; k0 += 32) {
        bf16x8 pa[2];
#pragma unroll
        for (int qt = 0; qt < 2; ++qt) {
            float* sp = Ab + (size_t)(qw + (qt << 4) + lr) * L + k0 + (lg << 3);
            const float4 s0 = *(const float4*)sp;
            const float4 s1 = *(const float4*)(sp + 4);
            const float M = Mq[qt], inv = Iq[qt];
            const float p0 = __expf(s0.x - M) * inv;
            const float p1 = __expf(s0.y - M) * inv;
            const float p2 = __expf(s0.z - M) * inv;
            const float p3 = __expf(s0.w - M) * inv;
            const float p4 = __expf(s1.x - M) * inv;
            const float p5 = __expf(s1.y - M) * inv;
            const float p6 = __expf(s1.z - M) * inv;
            const float p7 = __expf(s1.w - M) * inv;
            *(float4*)sp       = make_float4(p0, p1, p2, p3);   // final att
            *(float4*)(sp + 4) = make_float4(p4, p5, p6, p7);
            bf16x8 a;
            a[0] = (bf16)p0; a[1] = (bf16)p1; a[2] = (bf16)p2; a[3] = (bf16)p3;
            a[4] = (bf16)p4; a[5] = (bf16)p5; a[6] = (bf16)p6; a[7] = (bf16)p7;
            pa[qt] = a;
        }
        bf16x8 vb[4];
#pragma unroll
        for (int dt = 0; dt < 4; ++dt)
            vb[dt] = *(const bf16x8*)(Vb + (size_t)((dt << 4) + lr) * L + k0 + (lg << 3));
#pragma unroll
        for (int qt = 0; qt < 2; ++qt)
#pragma unroll
            for (int dt = 0; dt < 4; ++dt)
                acc[qt][dt] = __builtin_amdgcn_mfma_f32_16x16x32_bf16(
                    pa[qt], vb[dt], acc[qt][dt], 0, 0, 0);
    }

#pragma unroll
    for (int qt = 0; qt < 2; ++qt)
#pragma unroll
        for (int dt = 0; dt < 4; ++dt)
#pragma unroll
            for (int r = 0; r < 4; ++r) {
                const int row = qw + (qt << 4) + (lg << 2) + r;
                O[((size_t)bh * L + row) * 64 + (dt << 4) + lr] = acc[qt][dt][r];
            }
}

// ---------------------------------------------------------------------------
// FC: out[m,n] = sum_k Oflat[m,k]*Wfc[k,n] + bfc[n] + resid[m,n]  (fp32)
// ---------------------------------------------------------------------------
__global__ __launch_bounds__(256, 2)
void fc_kernel(const float* __restrict__ O, const float* __restrict__ Wfc,
               const float* __restrict__ bfc, const float* __restrict__ resid,
               float* __restrict__ out)
{
    __shared__ float As[128][64];
    __shared__ float Bs[64][128];
    const int tid = threadIdx.x;
    const int tx = tid & 15, ty = tid >> 4;
    const int m0 = blockIdx.x << 7;
    const int n0 = blockIdx.y << 7;
    float c[8][8] = {};

    for (int k0 = 0; k0 < HD; k0 += 64) {
        const int h = k0 >> 6;   // one head per k-tile
#pragma unroll
        for (int it = 0; it < 8; ++it) {
            const int idx = (it << 10) + (tid << 2);
            {
                const int r = idx >> 6, cb = idx & 63;
                const int m = m0 + r;
                const int b = m >> 11, l = m & (L - 1);
                *(float4*)&As[r][swzc(r, cb)] =
                    *(const float4*)(O + ((((size_t)b * H + h) * L + l) << 6) + cb);
            }
            {
                const int r = idx >> 7, cb = idx & 127;
                *(float4*)&Bs[r][cb] =
                    *(const float4*)(Wfc + (size_t)(k0 + r) * D + n0 + cb);
            }
        }
        __syncthreads();
        const int swA = (ty & 7) << 2;
#pragma unroll 2
        for (int kk = 0; kk < 64; kk += 4) {
            float4 a[8];
#pragma unroll
            for (int i = 0; i < 8; ++i)
                a[i] = *(const float4*)&As[(ty << 3) + i][kk ^ swA];
            float bl[4][4], bh_[4][4];
#pragma unroll
            for (int t = 0; t < 4; ++t) {
                const float4 b0 = *(const float4*)&Bs[kk + t][tx << 2];
                const float4 b1 = *(const float4*)&Bs[kk + t][(tx << 2) + 64];
                bl[t][0] = b0.x; bl[t][1] = b0.y; bl[t][2] = b0.z; bl[t][3] = b0.w;
                bh_[t][0] = b1.x; bh_[t][1] = b1.y; bh_[t][2] = b1.z; bh_[t][3] = b1.w;
            }
#pragma unroll
            for (int i = 0; i < 8; ++i) {
                const float af[4] = {a[i].x, a[i].y, a[i].z, a[i].w};
#pragma unroll
                for (int j = 0; j < 4; ++j)
#pragma unroll
                    for (int t = 0; t < 4; ++t) {
                        c[i][j]     = fmaf(af[t], bl[t][j], c[i][j]);
                        c[i][j + 4] = fmaf(af[t], bh_[t][j], c[i][j + 4]);
                    }
            }
        }
        __syncthreads();
    }

    const int nlo = n0 + (tx << 2);
    const int nhi = nlo + 64;
    const float4 blo = *(const float4*)(bfc + nlo);
    const float4 bhi = *(const float4*)(bfc + nhi);
#pragma unroll
    for (int i = 0; i < 8; ++i) {
        const int m = m0 + (ty << 3) + i;
        const float4 q0v = *(const float4*)(resid + (size_t)m * D + nlo);
        const float4 q1v = *(const float4*)(resid + (size_t)m * D + nhi);
        float4 r0, r1;
        r0.x = c[i][0] + blo.x + q0v.x; r0.y = c[i][1] + blo.y + q0v.y;
        r0.z = c[i][2] + blo.z + q0v.z; r0.w = c[i][3] + blo.w + q0v.w;
        r1.x = c[i][4] + bhi.x + q1v.x; r1.y = c[i][5] + bhi.y + q1v.y;
        r1.z = c[i][6] + bhi.z + q1v.z; r1.w = c[i][7] + bhi.w + q1v.w;
        *(float4*)(out + (size_t)m * D + nlo) = r0;
        *(float4*)(out + (size_t)m * D + nhi) = r1;
    }
}

}  // namespace

extern "C" void kernel_launch(void* const* d_in, const int* in_sizes, int n_in,
                              void* d_out, int out_size, void* d_ws, size_t ws_size,
                              hipStream_t stream)
{
    const float* q    = (const float*)d_in[0];
    const float* k    = (const float*)d_in[1];
    const float* v    = (const float*)d_in[2];
    const int*   mask = (const int*)d_in[3];
    const float* Wq   = (const float*)d_in[4];
    const float* bq   = (const float*)d_in[5];
    const float* Wk   = (const float*)d_in[6];
    const float* bk   = (const float*)d_in[7];
    const float* Wv   = (const float*)d_in[8];
    const float* bv   = (const float*)d_in[9];
    const float* Wfc  = (const float*)d_in[10];
    const float* bfc  = (const float*)d_in[11];

    float* out = (float*)d_out;                   // [B,L,D]
    float* att = out + (size_t)B * L * D;         // [B,H,L,L]

    bf16* Qh = (bf16*)d_ws;         // [bh][l][64] bf16, pre-scaled by 1/TEMP
    bf16* Kh = Qh + NH;             // [bh][l][64] bf16
    bf16* Vt = Kh + NH;             // [bh][d][L]  bf16 (transposed)
    float* O    = (float*)(Vt + NH);   // [bh][l][64] fp32
    float* stats = O + NH;             // [row] (max, 1/sum)
    float* part  = out;                // alias d_out: written only by fc at end
                                       // (NROWS*NJT*2 floats = 16.8 MB < 33.5 MB)

    const dim3 blk(256);

    gemm_proj<<<dim3(64, 8), blk, 0, stream>>>(q, Wq, bq, Qh, INV_TEMP, 0);
    gemm_proj<<<dim3(64, 8), blk, 0, stream>>>(k, Wk, bk, Kh, 1.0f, 0);
    gemm_proj<<<dim3(64, 8), blk, 0, stream>>>(v, Wv, bv, Vt, 1.0f, 1);

    scores_kernel<<<dim3(L / 128, L / 128, B * H), blk, 0, stream>>>(Qh, Kh, mask, att, part);
    rowstats_kernel<<<dim3(NROWS * 16 / 256), blk, 0, stream>>>(part, stats);
    attv_kernel<<<dim3(L / 128, B * H), blk, 0, stream>>>(att, Vt, stats, O);
    fc_kernel<<<dim3(64, 8), blk, 0, stream>>>(O, Wfc, bfc, q, out);
}

// Round 3
// 2301.299 us; speedup vs baseline: 1.9335x; 1.2187x over previous
//
#include <hip/hip_runtime.h>
#include <cstddef>

namespace {

constexpr int B  = 4;
constexpr int L  = 2048;
constexpr int D  = 1024;
constexpr int H  = 16;
constexpr int DK = 64;              // == DV
constexpr int HD = H * DK;          // 1024
constexpr float INV_TEMP = 0.125f;  // 1/8
constexpr size_t NH = (size_t)B * H * L * DK;  // 8,388,608 elements per head-tensor

typedef __bf16 bf16;
typedef bf16 bf16x4 __attribute__((ext_vector_type(4)));
typedef bf16 bf16x8 __attribute__((ext_vector_type(8)));
typedef float f32x4 __attribute__((ext_vector_type(4)));

// XOR swizzle for row-major [row][64] fp32 tiles read row-per-lane-group.
__device__ __forceinline__ int swzc(int r, int c) {
    return c ^ (((r >> 3) & 7) << 2);
}

// ---------------------------------------------------------------------------
// W (k-major [D][HD] fp32) -> Wt (n-major [HD][D] bf16), 64x64 LDS transpose.
// ---------------------------------------------------------------------------
__global__ __launch_bounds__(256)
void convW_kernel(const float* __restrict__ W, bf16* __restrict__ Wt)
{
    __shared__ float t[64][65];
    const int k0 = blockIdx.x << 6, n0 = blockIdx.y << 6;
    const int c = threadIdx.x & 63, r4 = threadIdx.x >> 6;
#pragma unroll
    for (int it = 0; it < 16; ++it) {
        const int r = (it << 2) + r4;
        t[r][c] = W[(size_t)(k0 + r) * HD + n0 + c];
    }
    __syncthreads();
#pragma unroll
    for (int it = 0; it < 16; ++it) {
        const int r = (it << 2) + r4;           // n-local
        Wt[(size_t)(n0 + r) * D + k0 + c] = (bf16)t[c][r];
    }
}

// ---------------------------------------------------------------------------
// fp32 -> bf16 elementwise (X staging). grid covers NH/4 float4s exactly.
// ---------------------------------------------------------------------------
__global__ __launch_bounds__(256)
void convX_kernel(const float* __restrict__ X, bf16* __restrict__ Xb)
{
    const size_t i = ((size_t)blockIdx.x * 256 + threadIdx.x) << 2;
    const float4 v = *(const float4*)(X + i);
    bf16x4 o;
    o[0] = (bf16)v.x; o[1] = (bf16)v.y; o[2] = (bf16)v.z; o[3] = (bf16)v.w;
    *(bf16x4*)(Xb + i) = o;
}

// ---------------------------------------------------------------------------
// Projection GEMM via bf16 MFMA, no LDS. Block = 128m x 64n, 4 waves (32m each).
// A = Xb [8192][1024] row-major, B = Wt [1024 n][1024 k].
//   vmode==0: outh[bh][l][64] bf16, scaled
//   vmode==1: transposed V: outh[bh][d][L] bf16
// bid: n-fastest so consecutive blocks share the A panel in L2.
// ---------------------------------------------------------------------------
__global__ __launch_bounds__(256, 2)
void proj_mfma(const bf16* __restrict__ Xb, const bf16* __restrict__ Wt,
               const float* __restrict__ bias, bf16* __restrict__ outh,
               float scale, int vmode)
{
    const int tid  = threadIdx.x;
    const int lane = tid & 63;
    const int w    = tid >> 6;
    const int lr   = lane & 15;
    const int lg   = lane >> 4;
    const int bid  = blockIdx.x;
    const int m0   = (bid >> 4) << 7;
    const int n0   = (bid & 15) << 6;
    const int mw   = m0 + (w << 5);

    f32x4 acc[2][4];
#pragma unroll
    for (int mt = 0; mt < 2; ++mt)
#pragma unroll
        for (int nt = 0; nt < 4; ++nt)
            acc[mt][nt] = (f32x4){0.f, 0.f, 0.f, 0.f};

    for (int k0 = 0; k0 < D; k0 += 32) {
        bf16x8 xa[2], wb[4];
#pragma unroll
        for (int mt = 0; mt < 2; ++mt)
            xa[mt] = *(const bf16x8*)(Xb + (size_t)(mw + (mt << 4) + lr) * D + k0 + (lg << 3));
#pragma unroll
        for (int nt = 0; nt < 4; ++nt)
            wb[nt] = *(const bf16x8*)(Wt + (size_t)(n0 + (nt << 4) + lr) * D + k0 + (lg << 3));
#pragma unroll
        for (int mt = 0; mt < 2; ++mt)
#pragma unroll
            for (int nt = 0; nt < 4; ++nt)
                acc[mt][nt] = __builtin_amdgcn_mfma_f32_16x16x32_bf16(
                    xa[mt], wb[nt], acc[mt][nt], 0, 0, 0);
    }

#pragma unroll
    for (int mt = 0; mt < 2; ++mt) {
        const int mbase = mw + (mt << 4) + (lg << 2);
        const int b     = mbase >> 11;
        const int lbase = mbase & (L - 1);
#pragma unroll
        for (int nt = 0; nt < 4; ++nt) {
            const int n = n0 + (nt << 4) + lr;
            const int h = n >> 6, d = n & 63;
            const float bj = bias[n];
            if (vmode) {
                bf16x4 vv;
#pragma unroll
                for (int r = 0; r < 4; ++r)
                    vv[r] = (bf16)((acc[mt][nt][r] + bj) * scale);
                *(bf16x4*)(outh + ((size_t)(b * H + h) * 64 + d) * L + lbase) = vv;
            } else {
#pragma unroll
                for (int r = 0; r < 4; ++r)
                    outh[(((size_t)(b * H + h) * L + lbase + r) << 6) + d] =
                        (bf16)((acc[mt][nt][r] + bj) * scale);
            }
        }
    }
}

// ---------------------------------------------------------------------------
// Fused attention: per block 128 q-rows x full j-range. No LDS, no barriers.
// Pass A: S^T = mfma(K,Q) -> online per-row (max, sum-exp), lane-local stats.
// Pass B: recompute S^T, normalize, write final att once, feed PV directly.
// P's k-slot bijection (lg,e) -> j = 16*(e>>2) + 4*lg + (e&3) is mirrored in
// the V-fragment loads from Vt[bh][d][L].
// ---------------------------------------------------------------------------
__global__ __launch_bounds__(256, 2)
void fused_attn(const bf16* __restrict__ Qh, const bf16* __restrict__ Kh,
                const bf16* __restrict__ Vt, const int* __restrict__ mask,
                float* __restrict__ att, float* __restrict__ O)
{
    const int tid  = threadIdx.x;
    const int lane = tid & 63;
    const int w    = tid >> 6;
    const int lr   = lane & 15;
    const int lg   = lane >> 4;
    const int q0   = blockIdx.x << 7;
    const int bh   = blockIdx.y;
    const int b    = bh >> 4;
    const int qw   = q0 + (w << 5);
    const bf16* Qb = Qh + (size_t)bh * L * DK;
    const bf16* Kb = Kh + (size_t)bh * L * DK;
    const bf16* Vb = Vt + (size_t)bh * DK * L;

    bf16x8 qf[2][2];
    const int* mrow[2];
    float* arow[2];
#pragma unroll
    for (int qt = 0; qt < 2; ++qt) {
        const int q = qw + (qt << 4) + lr;
#pragma unroll
        for (int kc = 0; kc < 2; ++kc)
            qf[qt][kc] = *(const bf16x8*)(Qb + (size_t)q * DK + (kc << 5) + (lg << 3));
        mrow[qt] = mask + ((size_t)b * L + q) * L;
        arow[qt] = att + ((size_t)bh * L + q) * L;
    }

    // ---- pass A: online row stats ----
    float mloc[2] = {-1e9f, -1e9f}, sloc[2] = {0.f, 0.f};
    for (int j0 = 0; j0 < L; j0 += 32) {
        bf16x8 kf[2][2];
#pragma unroll
        for (int jt = 0; jt < 2; ++jt)
#pragma unroll
            for (int kc = 0; kc < 2; ++kc)
                kf[jt][kc] = *(const bf16x8*)(Kb + (size_t)(j0 + (jt << 4) + lr) * DK + (kc << 5) + (lg << 3));
        f32x4 st[2][2];
#pragma unroll
        for (int qt = 0; qt < 2; ++qt)
#pragma unroll
            for (int jt = 0; jt < 2; ++jt)
                st[qt][jt] = (f32x4){0.f, 0.f, 0.f, 0.f};
#pragma unroll
        for (int kc = 0; kc < 2; ++kc)
#pragma unroll
            for (int qt = 0; qt < 2; ++qt)
#pragma unroll
                for (int jt = 0; jt < 2; ++jt)
                    st[qt][jt] = __builtin_amdgcn_mfma_f32_16x16x32_bf16(
                        kf[jt][kc], qf[qt][kc], st[qt][jt], 0, 0, 0);
#pragma unroll
        for (int qt = 0; qt < 2; ++qt) {
            float v[8];
            float cm = -1e9f;
#pragma unroll
            for (int jt = 0; jt < 2; ++jt)
#pragma unroll
                for (int r = 0; r < 4; ++r) {
                    const int j = j0 + (jt << 4) + (lg << 2) + r;
                    const float s = mrow[qt][j] ? st[qt][jt][r] : -1e9f;
                    v[(jt << 2) + r] = s;
                    cm = fmaxf(cm, s);
                }
            const float nm = fmaxf(mloc[qt], cm);
            float s8 = 0.f;
#pragma unroll
            for (int e = 0; e < 8; ++e) s8 += __expf(v[e] - nm);
            sloc[qt] = sloc[qt] * __expf(mloc[qt] - nm) + s8;
            mloc[qt] = nm;
        }
    }

    float M[2], inv[2];
#pragma unroll
    for (int qt = 0; qt < 2; ++qt) {
        float m_ = mloc[qt], s_ = sloc[qt];
#pragma unroll
        for (int off = 16; off < 64; off <<= 1) {
            const float mo = __shfl_xor(m_, off);
            const float so = __shfl_xor(s_, off);
            const float nm = fmaxf(m_, mo);
            s_ = s_ * __expf(m_ - nm) + so * __expf(mo - nm);
            m_ = nm;
        }
        M[qt] = m_;
        inv[qt] = 1.0f / s_;
    }

    // ---- pass B: recompute, write att, PV ----
    f32x4 pacc[2][4];
#pragma unroll
    for (int qt = 0; qt < 2; ++qt)
#pragma unroll
        for (int dt = 0; dt < 4; ++dt)
            pacc[qt][dt] = (f32x4){0.f, 0.f, 0.f, 0.f};

    for (int j0 = 0; j0 < L; j0 += 32) {
        bf16x8 kf[2][2];
#pragma unroll
        for (int jt = 0; jt < 2; ++jt)
#pragma unroll
            for (int kc = 0; kc < 2; ++kc)
                kf[jt][kc] = *(const bf16x8*)(Kb + (size_t)(j0 + (jt << 4) + lr) * DK + (kc << 5) + (lg << 3));
        f32x4 st[2][2];
#pragma unroll
        for (int qt = 0; qt < 2; ++qt)
#pragma unroll
            for (int jt = 0; jt < 2; ++jt)
                st[qt][jt] = (f32x4){0.f, 0.f, 0.f, 0.f};
#pragma unroll
        for (int kc = 0; kc < 2; ++kc)
#pragma unroll
            for (int qt = 0; qt < 2; ++qt)
#pragma unroll
                for (int jt = 0; jt < 2; ++jt)
                    st[qt][jt] = __builtin_amdgcn_mfma_f32_16x16x32_bf16(
                        kf[jt][kc], qf[qt][kc], st[qt][jt], 0, 0, 0);

        bf16x8 pf[2];
#pragma unroll
        for (int qt = 0; qt < 2; ++qt) {
#pragma unroll
            for (int jt = 0; jt < 2; ++jt)
#pragma unroll
                for (int r = 0; r < 4; ++r) {
                    const int j = j0 + (jt << 4) + (lg << 2) + r;
                    const float s = mrow[qt][j] ? st[qt][jt][r] : -1e9f;
                    const float p = __expf(s - M[qt]) * inv[qt];
                    arow[qt][j] = p;                  // final att (only write)
                    pf[qt][(jt << 2) + r] = (bf16)p;
                }
        }

        bf16x8 vf[4];
#pragma unroll
        for (int dt = 0; dt < 4; ++dt) {
            const bf16* vp = Vb + (size_t)((dt << 4) + lr) * L + j0 + (lg << 2);
            const bf16x4 v0 = *(const bf16x4*)vp;
            const bf16x4 v1 = *(const bf16x4*)(vp + 16);
            bf16x8 t;
            t[0] = v0[0]; t[1] = v0[1]; t[2] = v0[2]; t[3] = v0[3];
            t[4] = v1[0]; t[5] = v1[1]; t[6] = v1[2]; t[7] = v1[3];
            vf[dt] = t;
        }
#pragma unroll
        for (int qt = 0; qt < 2; ++qt)
#pragma unroll
            for (int dt = 0; dt < 4; ++dt)
                pacc[qt][dt] = __builtin_amdgcn_mfma_f32_16x16x32_bf16(
                    pf[qt], vf[dt], pacc[qt][dt], 0, 0, 0);
    }

#pragma unroll
    for (int qt = 0; qt < 2; ++qt)
#pragma unroll
        for (int dt = 0; dt < 4; ++dt)
#pragma unroll
            for (int r = 0; r < 4; ++r) {
                const int row = qw + (qt << 4) + (lg << 2) + r;
                O[((size_t)bh * L + row) * 64 + (dt << 4) + lr] = pacc[qt][dt][r];
            }
}

// ---------------------------------------------------------------------------
// FC: out[m,n] = sum_k Oflat[m,k]*Wfc[k,n] + bfc[n] + resid[m,n]  (fp32)
// ---------------------------------------------------------------------------
__global__ __launch_bounds__(256, 2)
void fc_kernel(const float* __restrict__ O, const float* __restrict__ Wfc,
               const float* __restrict__ bfc, const float* __restrict__ resid,
               float* __restrict__ out)
{
    __shared__ float As[128][64];
    __shared__ float Bs[64][128];
    const int tid = threadIdx.x;
    const int tx = tid & 15, ty = tid >> 4;
    const int m0 = blockIdx.x << 7;
    const int n0 = blockIdx.y << 7;
    float c[8][8] = {};

    for (int k0 = 0; k0 < HD; k0 += 64) {
        const int h = k0 >> 6;   // one head per k-tile
#pragma unroll
        for (int it = 0; it < 8; ++it) {
            const int idx = (it << 10) + (tid << 2);
            {
                const int r = idx >> 6, cb = idx & 63;
                const int m = m0 + r;
                const int b = m >> 11, l = m & (L - 1);
                *(float4*)&As[r][swzc(r, cb)] =
                    *(const float4*)(O + ((((size_t)b * H + h) * L + l) << 6) + cb);
            }
            {
                const int r = idx >> 7, cb = idx & 127;
                *(float4*)&Bs[r][cb] =
                    *(const float4*)(Wfc + (size_t)(k0 + r) * D + n0 + cb);
            }
        }
        __syncthreads();
        const int swA = (ty & 7) << 2;
#pragma unroll 2
        for (int kk = 0; kk < 64; kk += 4) {
            float4 a[8];
#pragma unroll
            for (int i = 0; i < 8; ++i)
                a[i] = *(const float4*)&As[(ty << 3) + i][kk ^ swA];
            float bl[4][4], bh_[4][4];
#pragma unroll
            for (int t = 0; t < 4; ++t) {
                const float4 b0 = *(const float4*)&Bs[kk + t][tx << 2];
                const float4 b1 = *(const float4*)&Bs[kk + t][(tx << 2) + 64];
                bl[t][0] = b0.x; bl[t][1] = b0.y; bl[t][2] = b0.z; bl[t][3] = b0.w;
                bh_[t][0] = b1.x; bh_[t][1] = b1.y; bh_[t][2] = b1.z; bh_[t][3] = b1.w;
            }
#pragma unroll
            for (int i = 0; i < 8; ++i) {
                const float af[4] = {a[i].x, a[i].y, a[i].z, a[i].w};
#pragma unroll
                for (int j = 0; j < 4; ++j)
#pragma unroll
                    for (int t = 0; t < 4; ++t) {
                        c[i][j]     = fmaf(af[t], bl[t][j], c[i][j]);
                        c[i][j + 4] = fmaf(af[t], bh_[t][j], c[i][j + 4]);
                    }
            }
        }
        __syncthreads();
    }

    const int nlo = n0 + (tx << 2);
    const int nhi = nlo + 64;
    const float4 blo = *(const float4*)(bfc + nlo);
    const float4 bhi = *(const float4*)(bfc + nhi);
#pragma unroll
    for (int i = 0; i < 8; ++i) {
        const int m = m0 + (ty << 3) + i;
        const float4 q0v = *(const float4*)(resid + (size_t)m * D + nlo);
        const float4 q1v = *(const float4*)(resid + (size_t)m * D + nhi);
        float4 r0, r1;
        r0.x = c[i][0] + blo.x + q0v.x; r0.y = c[i][1] + blo.y + q0v.y;
        r0.z = c[i][2] + blo.z + q0v.z; r0.w = c[i][3] + blo.w + q0v.w;
        r1.x = c[i][4] + bhi.x + q1v.x; r1.y = c[i][5] + bhi.y + q1v.y;
        r1.z = c[i][6] + bhi.z + q1v.z; r1.w = c[i][7] + bhi.w + q1v.w;
        *(float4*)(out + (size_t)m * D + nlo) = r0;
        *(float4*)(out + (size_t)m * D + nhi) = r1;
    }
}

}  // namespace

extern "C" void kernel_launch(void* const* d_in, const int* in_sizes, int n_in,
                              void* d_out, int out_size, void* d_ws, size_t ws_size,
                              hipStream_t stream)
{
    const float* q    = (const float*)d_in[0];
    const float* k    = (const float*)d_in[1];
    const float* v    = (const float*)d_in[2];
    const int*   mask = (const int*)d_in[3];
    const float* Wq   = (const float*)d_in[4];
    const float* bq   = (const float*)d_in[5];
    const float* Wk   = (const float*)d_in[6];
    const float* bk   = (const float*)d_in[7];
    const float* Wv   = (const float*)d_in[8];
    const float* bv   = (const float*)d_in[9];
    const float* Wfc  = (const float*)d_in[10];
    const float* bfc  = (const float*)d_in[11];

    float* out = (float*)d_out;                   // [B,L,D]
    float* att = out + (size_t)B * L * D;         // [B,H,L,L]

    // workspace layout (85.9 MB total):
    //   [0, NH floats)            O fp32 [bh][l][64]   (live: fused_attn -> fc)
    //   during projections, the O region is dead and hosts:
    //       Xb  bf16 NH           (input staging, reused q/k/v)
    //       Wt  bf16 3*D*HD       (transposed bf16 weights)
    //   [NH floats ...)           Qh, Kh, Vt bf16 head tensors
    float* O  = (float*)d_ws;
    bf16* Xb  = (bf16*)d_ws;
    bf16* Wtq = Xb + NH;
    bf16* Wtk = Wtq + (size_t)D * HD;
    bf16* Wtv = Wtk + (size_t)D * HD;
    bf16* Qh  = (bf16*)(O + NH);
    bf16* Kh  = Qh + NH;
    bf16* Vt  = Kh + NH;

    const dim3 blk(256);
    const dim3 gW(D / 64, HD / 64);
    const int gX = (int)(NH / 4 / 256);   // 8192
    const int gP = 1024;                  // 64 m-tiles x 16 n-tiles

    convW_kernel<<<gW, blk, 0, stream>>>(Wq, Wtq);
    convW_kernel<<<gW, blk, 0, stream>>>(Wk, Wtk);
    convW_kernel<<<gW, blk, 0, stream>>>(Wv, Wtv);

    convX_kernel<<<gX, blk, 0, stream>>>(q, Xb);
    proj_mfma<<<gP, blk, 0, stream>>>(Xb, Wtq, bq, Qh, INV_TEMP, 0);
    convX_kernel<<<gX, blk, 0, stream>>>(k, Xb);
    proj_mfma<<<gP, blk, 0, stream>>>(Xb, Wtk, bk, Kh, 1.0f, 0);
    convX_kernel<<<gX, blk, 0, stream>>>(v, Xb);
    proj_mfma<<<gP, blk, 0, stream>>>(Xb, Wtv, bv, Vt, 1.0f, 1);

    fused_attn<<<dim3(L / 128, B * H), blk, 0, stream>>>(Qh, Kh, Vt, mask, att, O);

    fc_kernel<<<dim3(64, 8), blk, 0, stream>>>(O, Wfc, bfc, q, out);
}